// Round 24
// baseline (169.171 us; speedup 1.0000x reference)
//
#include <hip/hip_runtime.h>

#define BATCH  8192
#define LATENT 128
#define HID    400
#define HIDP   448   // 7*64, zero-padded K (h and W2b both padded)
#define NOUT   4096
#define NE     16
#define HROWS  (BATCH + 256)
#define NCONV  2048  // convert blocks in k_mid (before 1008 layer1 blocks)

typedef __attribute__((ext_vector_type(8))) short bf16x8;
typedef __attribute__((ext_vector_type(4))) float f32x4;

__device__ __forceinline__ unsigned short f2bf(float f){
  unsigned u = __builtin_bit_cast(unsigned, f);
  u += 0x7fffu + ((u >> 16) & 1u);            // round-to-nearest-even
  return (unsigned short)(u >> 16);
}

__device__ __forceinline__ void gload16(const void* g, void* l){
  __builtin_amdgcn_global_load_lds(
      (const __attribute__((address_space(1))) void*)g,
      (__attribute__((address_space(3))) void*)l, 16, 0, 0);
}

// ---------------- bucket: hist + scan + scatter, one block ----------------
__global__ __launch_bounds__(1024) void k_bucket(const int* __restrict__ aidx, int* __restrict__ wsI){
  __shared__ int hist[NE];
  __shared__ int cursor[NE];
  int tid = threadIdx.x, lane = tid & 63;
  if (tid < NE) hist[tid] = 0;
  __syncthreads();

  int ev[8];
  #pragma unroll
  for (int c=0;c<8;c++) ev[c] = aidx[c*1024 + tid];

  #pragma unroll
  for (int c=0;c<8;c++){
    for (int x=0;x<NE;x++){
      unsigned long long m = __ballot(ev[c]==x);
      if (lane==0 && m) atomicAdd(&hist[x], (int)__popcll(m));
    }
  }
  __syncthreads();
  if (tid==0){
    int a=0;
    for (int x=0;x<NE;x++){ cursor[x]=a; wsI[32+x]=a; a+=hist[x]; }
    wsI[32+NE]=a;
  }
  __syncthreads();

  #pragma unroll
  for (int c=0;c<8;c++){
    int e = ev[c], i = c*1024 + tid;
    for (int x=0;x<NE;x++){
      unsigned long long m = __ballot(e==x);
      if (m){
        int leader = __ffsll((unsigned long long)m) - 1;
        int base = 0;
        if (lane == leader) base = atomicAdd(&cursor[x], (int)__popcll(m));
        base = __shfl(base, leader);
        if (e==x){
          int rank = (int)__popcll(m & ((1ull<<lane)-1ull));
          wsI[64 + base + rank] = i;
        }
      }
    }
  }
}

// ---------------- mid: blocks 0..NCONV-1 = flat padded W2 convert; rest = layer1 ----------------
// layer1 uses only 16.4 KB static LDS so co-resident convert blocks run at
// full occupancy (round-21 lesson: all blocks inherit max static LDS).
__global__ __launch_bounds__(256) void k_mid(
    const float* __restrict__ z, const float* __restrict__ W1, const float* __restrict__ b1,
    const int* __restrict__ wsI, unsigned short* __restrict__ hws,
    const float* __restrict__ W2, unsigned short* __restrict__ W2b)
{
  int tid = threadIdx.x;
  if (blockIdx.x < NCONV){
    const int NSLOT = NE*NOUT*(HIDP/8);        // 3,670,016 slots of 8 bf16
    int g = (int)blockIdx.x*256 + tid;
    for (int i = g; i < NSLOT; i += NCONV*256){
      int row  = (int)((unsigned)i / 56u);
      int slot = i - row*56;
      int k = slot*8;
      bf16x8 w = (bf16x8){0,0,0,0,0,0,0,0};
      if (slot < 50){
        const float* s = W2 + (size_t)row*HID + k;
        f32x4 a = __builtin_nontemporal_load((const f32x4*)s);
        f32x4 b = __builtin_nontemporal_load((const f32x4*)(s+4));
        w[0]=(short)f2bf(a.x); w[1]=(short)f2bf(a.y); w[2]=(short)f2bf(a.z); w[3]=(short)f2bf(a.w);
        w[4]=(short)f2bf(b.x); w[5]=(short)f2bf(b.y); w[6]=(short)f2bf(b.z); w[7]=(short)f2bf(b.w);
      }
      __builtin_nontemporal_store(w, (bf16x8*)(W2b + (size_t)row*HIDP + k));
    }
    return;
  }

  // ---- layer 1: h = relu(z @ W1[e]^T + b1[e]); 64x64 tile, 2 K-steps of 64 ----
  __shared__ int s_off[NE+1];
  __shared__ int s_perm[64];
  __shared__ unsigned short As[64*64];   // 8 KB, 128B swizzled rows
  __shared__ unsigned short Bs[64*64];   // 8 KB
  if (tid <= NE) s_off[tid] = wsI[32+tid];
  __syncthreads();

  int b2i = (int)blockIdx.x - NCONV;
  int rt = b2i / 7;
  int n0 = (b2i % 7) * 64;

  int e=-1, tile=0;
  { int acc=0;
    for (int i=0;i<NE;i++){
      int cnt = s_off[i+1]-s_off[i]; int t = (cnt+63)>>6;
      if (rt < acc+t){ e=i; tile=rt-acc; break; }
      acc += t; } }
  if (e < 0) return;
  int r0 = s_off[e] + tile*64;
  int rows = s_off[e+1] - r0; if (rows > 64) rows = 64;

  if (tid < 64) s_perm[tid] = (tid < rows) ? wsI[64 + r0 + tid] : 0;
  __syncthreads();

  int lane = tid & 63, wid = tid >> 6;
  int wm = wid >> 1, wn = wid & 1;
  int llo = lane & 15, lhi = lane >> 4;
  const float* w1e = W1 + (size_t)e*HID*LATENT;
  f32x4 acc[2][2];
  #pragma unroll
  for (int i=0;i<2;i++)
    #pragma unroll
    for (int j=0;j<2;j++) acc[i][j] = (f32x4){0.f,0.f,0.f,0.f};

  #pragma unroll
  for (int kk=0; kk<2; kk++){
    if (kk) __syncthreads();               // protect previous K-step reads
    // stage A (gathered z) and B (W1), fp32 -> bf16, swizzled 128B rows
    #pragma unroll
    for (int p=0;p<4;p++){
      int id = tid + p*256; int row = id>>4, c4 = id&15;
      float4 v = make_float4(0.f,0.f,0.f,0.f);
      if (row < rows) v = *(const float4*)(z + (size_t)s_perm[row]*LATENT + kk*64 + c4*4);
      short4 w; w.x=(short)f2bf(v.x); w.y=(short)f2bf(v.y); w.z=(short)f2bf(v.z); w.w=(short)f2bf(v.w);
      *(short4*)((char*)As + row*128 + ((c4*8) ^ ((row&7)<<4))) = w;
    }
    #pragma unroll
    for (int p=0;p<4;p++){
      int id = tid + p*256; int row = id>>4, c4 = id&15;
      int n = n0 + row;
      float4 v = make_float4(0.f,0.f,0.f,0.f);
      if (n < HID) v = *(const float4*)(w1e + (size_t)n*LATENT + kk*64 + c4*4);
      short4 w; w.x=(short)f2bf(v.x); w.y=(short)f2bf(v.y); w.z=(short)f2bf(v.z); w.w=(short)f2bf(v.w);
      *(short4*)((char*)Bs + row*128 + ((c4*8) ^ ((row&7)<<4))) = w;
    }
    __syncthreads();
    #pragma unroll
    for (int s=0;s<2;s++){
      bf16x8 af[2], bfr[2];
      #pragma unroll
      for (int i=0;i<2;i++){ int m = wm*32 + i*16 + llo;
        af[i] = *(bf16x8*)((char*)As + m*128 + ((s*64 + lhi*16) ^ ((m&7)<<4))); }
      #pragma unroll
      for (int j=0;j<2;j++){ int n = wn*32 + j*16 + llo;
        bfr[j] = *(bf16x8*)((char*)Bs + n*128 + ((s*64 + lhi*16) ^ ((n&7)<<4))); }
      #pragma unroll
      for (int i=0;i<2;i++)
        #pragma unroll
        for (int j=0;j<2;j++)
          acc[i][j] = __builtin_amdgcn_mfma_f32_16x16x32_bf16(af[i], bfr[j], acc[i][j], 0,0,0);
    }
  }

  const float* b1e = b1 + e*HID;
  #pragma unroll
  for (int i=0;i<2;i++){
    #pragma unroll
    for (int j=0;j<2;j++){
      int n = n0 + wn*32 + j*16 + llo;
      float bias = (n < HID) ? b1e[n] : 0.f;
      #pragma unroll
      for (int q=0;q<4;q++){
        int m = wm*32 + i*16 + lhi*4 + q;
        if (m < rows){
          float v = acc[i][j][q] + bias;
          v = (v > 0.f) ? v : 0.f;
          if (n >= HID) v = 0.f;
          hws[(size_t)(r0+m)*HIDP + n] = f2bf(v);
        }
      }
    }
  }
}

// ---------------- layer 2: out = sigmoid(h @ W2b[e]^T + b2[e]) ----------------
// Round-23 measured-best: BM=256 x BN=128, BK=64 (7 iters), 512 thr / 8 waves
// (4m x 2n of 64x64), single-buffered 48KB LDS, STAGE -> syncthreads -> MFMA ->
// syncthreads. BY-FAST XCD-chunked dispatch (32 consecutive blocks/XCD share
// one A row-tile). Pre-swizzled gload_lds source. nt out stores.
__global__ __launch_bounds__(512) void k_layer2(
    const unsigned short* __restrict__ hws, const unsigned short* __restrict__ W2b,
    const float* __restrict__ b2, const int* __restrict__ wsI, float* __restrict__ out)
{
  __shared__ int s_off[NE+1];
  __shared__ int s_perm[256];
  __shared__ unsigned short As[256*64];   // 32 KB
  __shared__ unsigned short Bs[128*64];   // 16 KB
  int tid = threadIdx.x;
  if (tid <= NE) s_off[tid] = wsI[32+tid];
  __syncthreads();

  int lin = (int)blockIdx.x;              // 1536 = 8 * 192; 192 = 6 bx * 32 by
  int logical = (lin & 7) * 192 + (lin >> 3);
  int by = logical & 31;                  // FAST: 32 consecutive blocks share bx
  int bx = logical >> 5;                  // 0..47

  int e=-1, tile=0;
  { int acc=0;
    for (int i=0;i<NE;i++){
      int cnt = s_off[i+1]-s_off[i]; int t = (cnt+255)>>8;
      if (bx < acc+t){ e=i; tile=bx-acc; break; }
      acc += t; } }
  if (e < 0) return;
  int r0 = s_off[e] + tile*256;
  int rows = s_off[e+1] - r0; if (rows > 256) rows = 256;
  int n0 = by * 128;
  if (tid < 256) s_perm[tid] = (tid < rows) ? wsI[64 + r0 + tid] : 0;

  int lane = tid & 63, w = tid >> 6;      // 8 waves
  int srow = lane >> 3;
  int colU = (lane & 7) ^ srow;
  const unsigned short* aSrcBase = hws + (size_t)r0*HIDP + colU*8;
  const unsigned short* bSrcBase = W2b + ((size_t)e*NOUT + n0)*HIDP + colU*8;

  int wm = w >> 1, wn = w & 1;            // 4m x 2n -> wave tile 64x64
  int llo = lane & 15, lhi = lane >> 4;
  f32x4 acc[4][4];
  #pragma unroll
  for (int i=0;i<4;i++)
    #pragma unroll
    for (int j=0;j<4;j++) acc[i][j] = (f32x4){0.f,0.f,0.f,0.f};

  #define STAGE(K0) { \
    _Pragma("unroll") for (int p=0;p<4;p++){ \
      int c = w*4 + p; int row = c*8 + srow; \
      gload16(aSrcBase + (size_t)row*HIDP + (K0), &As[c*512]); } \
    _Pragma("unroll") for (int p=0;p<2;p++){ \
      int c = w*2 + p; int row = c*8 + srow; \
      gload16(bSrcBase + (size_t)row*HIDP + (K0), &Bs[c*512]); } }

  for (int kt=0; kt<7; kt++){
    STAGE(kt*64);
    __syncthreads();                         // vmcnt(0) drain + barrier (m97 pattern)
    #pragma unroll
    for (int s=0;s<2;s++){
      bf16x8 af[4], bfr[4];
      #pragma unroll
      for (int i=0;i<4;i++){ int m = wm*64 + i*16 + llo;
        af[i] = *(bf16x8*)((char*)As + m*128 + ((s*64 + lhi*16) ^ ((m&7)<<4))); }
      #pragma unroll
      for (int j=0;j<4;j++){ int n = wn*64 + j*16 + llo;
        bfr[j] = *(bf16x8*)((char*)Bs + n*128 + ((s*64 + lhi*16) ^ ((n&7)<<4))); }
      #pragma unroll
      for (int i=0;i<4;i++)
        #pragma unroll
        for (int j=0;j<4;j++)
          acc[i][j] = __builtin_amdgcn_mfma_f32_16x16x32_bf16(af[i], bfr[j], acc[i][j], 0,0,0);
    }
    __syncthreads();                         // all waves done reading before next STAGE
  }

  const float* b2e = b2 + (size_t)e*NOUT;
  #pragma unroll
  for (int i=0;i<4;i++){
    int mb = wm*64 + i*16 + lhi*4;
    #pragma unroll
    for (int q=0;q<4;q++){
      int m = mb + q;
      if (m < rows){
        int orow = s_perm[m];
        float* op = out + (size_t)orow*NOUT + n0;
        #pragma unroll
        for (int j=0;j<4;j++){
          int nloc = wn*64 + j*16 + llo;
          float x = acc[i][j][q] + b2e[n0 + nloc];
          __builtin_nontemporal_store(1.f / (1.f + __expf(-x)), op + nloc);
        }
      }
    }
  }
}

extern "C" void kernel_launch(void* const* d_in, const int* in_sizes, int n_in,
                              void* d_out, int out_size, void* d_ws, size_t ws_size,
                              hipStream_t stream){
  const float* z   = (const float*)d_in[0];
  const float* W1  = (const float*)d_in[1];
  const float* b1  = (const float*)d_in[2];
  const float* W2  = (const float*)d_in[3];
  const float* b2  = (const float*)d_in[4];
  const int*  aidx = (const int*)d_in[5];
  float* out = (float*)d_out;
  int* wsI = (int*)d_ws;
  unsigned short* hws = (unsigned short*)((char*)d_ws + 65536);
  unsigned short* W2b = (unsigned short*)((char*)d_ws + 65536 + (size_t)HROWS*HIDP*2);

  k_bucket<<<1, 1024, 0, stream>>>(aidx, wsI);
  k_mid   <<<NCONV + 1008, 256, 0, stream>>>(z, W1, b1, wsI, hws, W2, W2b); // convert || layer1
  k_layer2<<<1536, 512, 0, stream>>>(hws, W2b, b2, wsI, out); // 8 xcd x (6 bx x 32 by), by fast
}

// Round 25
// 141.583 us; speedup vs baseline: 1.1949x; 1.1949x over previous
//
#include <hip/hip_runtime.h>

#define BATCH  8192
#define LATENT 128
#define HID    400
#define HIDP   448   // 7*64, zero-padded K (h and W2b both padded)
#define NOUT   4096
#define NE     16
#define HROWS  (BATCH + 256)

typedef __attribute__((ext_vector_type(8))) short bf16x8;
typedef __attribute__((ext_vector_type(4))) float f32x4;

__device__ __forceinline__ unsigned short f2bf(float f){
  unsigned u = __builtin_bit_cast(unsigned, f);
  u += 0x7fffu + ((u >> 16) & 1u);            // round-to-nearest-even
  return (unsigned short)(u >> 16);
}

__device__ __forceinline__ void gload16(const void* g, void* l){
  __builtin_amdgcn_global_load_lds(
      (const __attribute__((address_space(1))) void*)g,
      (__attribute__((address_space(3))) void*)l, 16, 0, 0);
}

// ---------------- prep: block 0 = bucket; blocks 1..1536 = flat PADDED W2 fp32->bf16 ----------------
__global__ __launch_bounds__(1024) void k_prep(
    const int* __restrict__ aidx, int* __restrict__ wsI,
    const float* __restrict__ W2, unsigned short* __restrict__ W2b)
{
  int tid = threadIdx.x;
  if (blockIdx.x != 0){
    const int NSLOT = NE*NOUT*(HIDP/8);        // 3,670,016 slots of 8 bf16
    int g = ((int)blockIdx.x - 1)*1024 + tid;
    for (int i = g; i < NSLOT; i += 1536*1024){
      int row  = (int)((unsigned)i / 56u);
      int slot = i - row*56;
      int k = slot*8;
      bf16x8 w = (bf16x8){0,0,0,0,0,0,0,0};
      if (slot < 50){
        const float* s = W2 + (size_t)row*HID + k;
        f32x4 a = __builtin_nontemporal_load((const f32x4*)s);
        f32x4 b = __builtin_nontemporal_load((const f32x4*)(s+4));
        w[0]=(short)f2bf(a.x); w[1]=(short)f2bf(a.y); w[2]=(short)f2bf(a.z); w[3]=(short)f2bf(a.w);
        w[4]=(short)f2bf(b.x); w[5]=(short)f2bf(b.y); w[6]=(short)f2bf(b.z); w[7]=(short)f2bf(b.w);
      }
      __builtin_nontemporal_store(w, (bf16x8*)(W2b + (size_t)row*HIDP + k));
    }
    return;
  }
  // ---- bucket ----
  __shared__ int hist[NE];
  __shared__ int cursor[NE];
  int lane = tid & 63;
  if (tid < NE) hist[tid] = 0;
  __syncthreads();

  int ev[8];
  #pragma unroll
  for (int c=0;c<8;c++) ev[c] = aidx[c*1024 + tid];

  #pragma unroll
  for (int c=0;c<8;c++){
    for (int x=0;x<NE;x++){
      unsigned long long m = __ballot(ev[c]==x);
      if (lane==0 && m) atomicAdd(&hist[x], (int)__popcll(m));
    }
  }
  __syncthreads();
  if (tid==0){
    int a=0;
    for (int x=0;x<NE;x++){ cursor[x]=a; wsI[32+x]=a; a+=hist[x]; }
    wsI[32+NE]=a;
  }
  __syncthreads();

  #pragma unroll
  for (int c=0;c<8;c++){
    int e = ev[c], i = c*1024 + tid;
    for (int x=0;x<NE;x++){
      unsigned long long m = __ballot(e==x);
      if (m){
        int leader = __ffsll((unsigned long long)m) - 1;
        int base = 0;
        if (lane == leader) base = atomicAdd(&cursor[x], (int)__popcll(m));
        base = __shfl(base, leader);
        if (e==x){
          int rank = (int)__popcll(m & ((1ull<<lane)-1ull));
          wsI[64 + base + rank] = i;
        }
      }
    }
  }
}

// ---------------- layer 1: h = relu(z @ W1[e]^T + b1[e]) ----------------
__global__ __launch_bounds__(256) void k_layer1(
    const float* __restrict__ z, const float* __restrict__ W1, const float* __restrict__ b1,
    const int* __restrict__ wsI, unsigned short* __restrict__ hws)
{
  __shared__ int s_off[NE+1];
  __shared__ int s_perm[64];
  __shared__ unsigned short As[64*128];
  __shared__ unsigned short Bs[64*128];
  int tid = threadIdx.x;
  if (tid <= NE) s_off[tid] = wsI[32+tid];
  __syncthreads();

  int e=-1, tile=0;
  { int acc=0;
    for (int i=0;i<NE;i++){
      int cnt = s_off[i+1]-s_off[i]; int t = (cnt+63)>>6;
      if ((int)blockIdx.x < acc+t){ e=i; tile=(int)blockIdx.x-acc; break; }
      acc += t; } }
  if (e < 0) return;
  int r0 = s_off[e] + tile*64;
  int rows = s_off[e+1] - r0; if (rows > 64) rows = 64;
  int n0 = blockIdx.y * 64;

  if (tid < 64) s_perm[tid] = (tid < rows) ? wsI[64 + r0 + tid] : 0;
  __syncthreads();

  #pragma unroll
  for (int p=0;p<8;p++){
    int id = tid + p*256; int row = id>>5, c4 = id&31;
    float4 v = make_float4(0.f,0.f,0.f,0.f);
    if (row < rows) v = *(const float4*)(z + (size_t)s_perm[row]*LATENT + c4*4);
    short4 w; w.x=(short)f2bf(v.x); w.y=(short)f2bf(v.y); w.z=(short)f2bf(v.z); w.w=(short)f2bf(v.w);
    *(short4*)((char*)As + row*256 + ((c4*8) ^ ((row&7)<<4))) = w;
  }
  const float* w1e = W1 + (size_t)e*HID*LATENT;
  #pragma unroll
  for (int p=0;p<8;p++){
    int id = tid + p*256; int row = id>>5, c4 = id&31;
    int n = n0 + row;
    float4 v = make_float4(0.f,0.f,0.f,0.f);
    if (n < HID) v = *(const float4*)(w1e + (size_t)n*LATENT + c4*4);
    short4 w; w.x=(short)f2bf(v.x); w.y=(short)f2bf(v.y); w.z=(short)f2bf(v.z); w.w=(short)f2bf(v.w);
    *(short4*)((char*)Bs + row*256 + ((c4*8) ^ ((row&7)<<4))) = w;
  }
  __syncthreads();

  int lane = tid & 63, wid = tid >> 6;
  int wm = wid >> 1, wn = wid & 1;
  int llo = lane & 15, lhi = lane >> 4;
  f32x4 acc[2][2];
  #pragma unroll
  for (int i=0;i<2;i++)
    #pragma unroll
    for (int j=0;j<2;j++) acc[i][j] = (f32x4){0.f,0.f,0.f,0.f};

  #pragma unroll
  for (int s=0;s<4;s++){
    bf16x8 af[2], bfr[2];
    #pragma unroll
    for (int i=0;i<2;i++){ int m = wm*32 + i*16 + llo;
      af[i] = *(bf16x8*)((char*)As + m*256 + ((s*64 + lhi*16) ^ ((m&7)<<4))); }
    #pragma unroll
    for (int j=0;j<2;j++){ int n = wn*32 + j*16 + llo;
      bfr[j] = *(bf16x8*)((char*)Bs + n*256 + ((s*64 + lhi*16) ^ ((n&7)<<4))); }
    #pragma unroll
    for (int i=0;i<2;i++)
      #pragma unroll
      for (int j=0;j<2;j++)
        acc[i][j] = __builtin_amdgcn_mfma_f32_16x16x32_bf16(af[i], bfr[j], acc[i][j], 0,0,0);
  }

  const float* b1e = b1 + e*HID;
  #pragma unroll
  for (int i=0;i<2;i++){
    #pragma unroll
    for (int j=0;j<2;j++){
      int n = n0 + wn*32 + j*16 + llo;
      float bias = (n < HID) ? b1e[n] : 0.f;
      #pragma unroll
      for (int q=0;q<4;q++){
        int m = wm*32 + i*16 + lhi*4 + q;
        if (m < rows){
          float v = acc[i][j][q] + bias;
          v = (v > 0.f) ? v : 0.f;
          if (n >= HID) v = 0.f;
          hws[(size_t)(r0+m)*HIDP + n] = f2bf(v);
        }
      }
    }
  }
}

// ---------------- layer 2: out = sigmoid(h @ W2b[e]^T + b2[e]) ----------------
// Measured-best (round 23): BM=256 x BN=128, BK=64 (7 iters), 512 thr / 8 waves
// (4m x 2n of 64x64), single-buffered 48KB LDS, STAGE -> syncthreads -> MFMA ->
// syncthreads. BY-FAST XCD-chunked dispatch: the 32 consecutive blocks per XCD
// share ONE A row-tile (L2-resident) -> FETCH ~52MB (~unique bytes).
// Pre-swizzled gload_lds source. nt out stores.
__global__ __launch_bounds__(512) void k_layer2(
    const unsigned short* __restrict__ hws, const unsigned short* __restrict__ W2b,
    const float* __restrict__ b2, const int* __restrict__ wsI, float* __restrict__ out)
{
  __shared__ int s_off[NE+1];
  __shared__ int s_perm[256];
  __shared__ unsigned short As[256*64];   // 32 KB
  __shared__ unsigned short Bs[128*64];   // 16 KB
  int tid = threadIdx.x;
  if (tid <= NE) s_off[tid] = wsI[32+tid];
  __syncthreads();

  int lin = (int)blockIdx.x;              // 1536 = 8 * 192; 192 = 6 bx * 32 by
  int logical = (lin & 7) * 192 + (lin >> 3);
  int by = logical & 31;                  // FAST: 32 consecutive blocks share bx
  int bx = logical >> 5;                  // 0..47

  int e=-1, tile=0;
  { int acc=0;
    for (int i=0;i<NE;i++){
      int cnt = s_off[i+1]-s_off[i]; int t = (cnt+255)>>8;
      if (bx < acc+t){ e=i; tile=bx-acc; break; }
      acc += t; } }
  if (e < 0) return;
  int r0 = s_off[e] + tile*256;
  int rows = s_off[e+1] - r0; if (rows > 256) rows = 256;
  int n0 = by * 128;
  if (tid < 256) s_perm[tid] = (tid < rows) ? wsI[64 + r0 + tid] : 0;

  int lane = tid & 63, w = tid >> 6;      // 8 waves
  int srow = lane >> 3;
  int colU = (lane & 7) ^ srow;
  const unsigned short* aSrcBase = hws + (size_t)r0*HIDP + colU*8;
  const unsigned short* bSrcBase = W2b + ((size_t)e*NOUT + n0)*HIDP + colU*8;

  int wm = w >> 1, wn = w & 1;            // 4m x 2n -> wave tile 64x64
  int llo = lane & 15, lhi = lane >> 4;
  f32x4 acc[4][4];
  #pragma unroll
  for (int i=0;i<4;i++)
    #pragma unroll
    for (int j=0;j<4;j++) acc[i][j] = (f32x4){0.f,0.f,0.f,0.f};

  #define STAGE(K0) { \
    _Pragma("unroll") for (int p=0;p<4;p++){ \
      int c = w*4 + p; int row = c*8 + srow; \
      gload16(aSrcBase + (size_t)row*HIDP + (K0), &As[c*512]); } \
    _Pragma("unroll") for (int p=0;p<2;p++){ \
      int c = w*2 + p; int row = c*8 + srow; \
      gload16(bSrcBase + (size_t)row*HIDP + (K0), &Bs[c*512]); } }

  for (int kt=0; kt<7; kt++){
    STAGE(kt*64);
    __syncthreads();                         // vmcnt(0) drain + barrier (m97 pattern)
    #pragma unroll
    for (int s=0;s<2;s++){
      bf16x8 af[4], bfr[4];
      #pragma unroll
      for (int i=0;i<4;i++){ int m = wm*64 + i*16 + llo;
        af[i] = *(bf16x8*)((char*)As + m*128 + ((s*64 + lhi*16) ^ ((m&7)<<4))); }
      #pragma unroll
      for (int j=0;j<4;j++){ int n = wn*64 + j*16 + llo;
        bfr[j] = *(bf16x8*)((char*)Bs + n*128 + ((s*64 + lhi*16) ^ ((n&7)<<4))); }
      #pragma unroll
      for (int i=0;i<4;i++)
        #pragma unroll
        for (int j=0;j<4;j++)
          acc[i][j] = __builtin_amdgcn_mfma_f32_16x16x32_bf16(af[i], bfr[j], acc[i][j], 0,0,0);
    }
    __syncthreads();                         // all waves done reading before next STAGE
  }

  const float* b2e = b2 + (size_t)e*NOUT;
  #pragma unroll
  for (int i=0;i<4;i++){
    int mb = wm*64 + i*16 + lhi*4;
    #pragma unroll
    for (int q=0;q<4;q++){
      int m = mb + q;
      if (m < rows){
        int orow = s_perm[m];
        float* op = out + (size_t)orow*NOUT + n0;
        #pragma unroll
        for (int j=0;j<4;j++){
          int nloc = wn*64 + j*16 + llo;
          float x = acc[i][j][q] + b2e[n0 + nloc];
          __builtin_nontemporal_store(1.f / (1.f + __expf(-x)), op + nloc);
        }
      }
    }
  }
}

extern "C" void kernel_launch(void* const* d_in, const int* in_sizes, int n_in,
                              void* d_out, int out_size, void* d_ws, size_t ws_size,
                              hipStream_t stream){
  const float* z   = (const float*)d_in[0];
  const float* W1  = (const float*)d_in[1];
  const float* b1  = (const float*)d_in[2];
  const float* W2  = (const float*)d_in[3];
  const float* b2  = (const float*)d_in[4];
  const int*  aidx = (const int*)d_in[5];
  float* out = (float*)d_out;
  int* wsI = (int*)d_ws;
  unsigned short* hws = (unsigned short*)((char*)d_ws + 65536);
  unsigned short* W2b = (unsigned short*)((char*)d_ws + 65536 + (size_t)HROWS*HIDP*2);

  k_prep  <<<1537, 1024, 0, stream>>>(aidx, wsI, W2, W2b);   // bucket || flat padded convert
  k_layer1<<<dim3(144, 7), 256, 0, stream>>>(z, W1, b1, wsI, hws);
  k_layer2<<<1536, 512, 0, stream>>>(hws, W2b, b2, wsI, out); // 8 xcd x (6 bx x 32 by), by fast
}